// Round 8
// baseline (167.133 us; speedup 1.0000x reference)
//
#include <hip/hip_runtime.h>

typedef __bf16 bf16x8 __attribute__((ext_vector_type(8)));
typedef float floatx4 __attribute__((ext_vector_type(4)));

// two float4 (8 fp32) -> bf16 hi + lo fragments
__device__ inline void cvt8_hl_r(float4 v0, float4 v1, bf16x8& h, bf16x8& l){
  float v[8] = {v0.x, v0.y, v0.z, v0.w, v1.x, v1.y, v1.z, v1.w};
  #pragma unroll
  for (int i = 0; i < 8; ++i) {
    __bf16 hi = (__bf16)v[i];
    h[i] = hi;
    l[i] = (__bf16)(v[i] - (float)hi);
  }
}
__device__ inline void cvt8_hl(const float* __restrict__ p, bf16x8& h, bf16x8& l){
  cvt8_hl_r(*reinterpret_cast<const float4*>(p),
            *reinterpret_cast<const float4*>(p + 4), h, l);
}

// ---------------------------------------------------------------------------
// K1: partial GEMM. grid (512 ff-blocks, 2 k-halves). Each block: 16 ff,
// K=512 split 4 ways across waves (128 each). ALL W loads hoisted up front
// (16 float4/wave in flight) to fix the load->cvt->MFMA serialization seen
// at VGPR=44 (rounds 6/7: 97% latency stall). Partials to pT/pG; silu in k1c.
// ---------------------------------------------------------------------------
__global__ __launch_bounds__(256) void k1_gemm(
    const float* __restrict__ x,
    const float* __restrict__ Wt,
    const float* __restrict__ Wg,
    float* __restrict__ pT, float* __restrict__ pG)
{
  __shared__ float red[3][32][64];
  const int tid  = threadIdx.x;
  const int wave = tid >> 6, lane = tid & 63;
  const int quad = lane >> 4, r16 = lane & 15;
  const int ff = blockIdx.x * 16 + r16;
  const int kb = blockIdx.y * 512 + wave * 128 + quad * 8;

  floatx4 accT[4], accG[4];
  #pragma unroll
  for (int m = 0; m < 4; ++m) { accT[m] = (floatx4)0.0f; accG[m] = (floatx4)0.0f; }

  const float* wt = Wt + ff * 1024 + kb;
  const float* wg = Wg + ff * 1024 + kb;
  const float* xp = x  + r16 * 1024 + kb;

  // hoist all W loads: 4 iters x (wt 2 + wg 2) float4 -> 16 outstanding loads
  float4 wtv[8], wgv[8];
  #pragma unroll
  for (int it = 0; it < 4; ++it) {
    wtv[it * 2]     = *reinterpret_cast<const float4*>(wt + it * 32);
    wtv[it * 2 + 1] = *reinterpret_cast<const float4*>(wt + it * 32 + 4);
    wgv[it * 2]     = *reinterpret_cast<const float4*>(wg + it * 32);
    wgv[it * 2 + 1] = *reinterpret_cast<const float4*>(wg + it * 32 + 4);
  }

  #pragma unroll
  for (int it = 0; it < 4; ++it) {
    bf16x8 bth, btl, bgh, bgl;
    cvt8_hl_r(wtv[it * 2], wtv[it * 2 + 1], bth, btl);
    cvt8_hl_r(wgv[it * 2], wgv[it * 2 + 1], bgh, bgl);
    #pragma unroll
    for (int mt = 0; mt < 4; ++mt) {
      bf16x8 ah, al;
      cvt8_hl(xp + mt * 16384 + it * 32, ah, al);
      accT[mt] = __builtin_amdgcn_mfma_f32_16x16x32_bf16(ah, bth, accT[mt], 0, 0, 0);
      accT[mt] = __builtin_amdgcn_mfma_f32_16x16x32_bf16(ah, btl, accT[mt], 0, 0, 0);
      accT[mt] = __builtin_amdgcn_mfma_f32_16x16x32_bf16(al, bth, accT[mt], 0, 0, 0);
      accG[mt] = __builtin_amdgcn_mfma_f32_16x16x32_bf16(ah, bgh, accG[mt], 0, 0, 0);
      accG[mt] = __builtin_amdgcn_mfma_f32_16x16x32_bf16(ah, bgl, accG[mt], 0, 0, 0);
      accG[mt] = __builtin_amdgcn_mfma_f32_16x16x32_bf16(al, bgh, accG[mt], 0, 0, 0);
    }
  }

  if (wave != 0) {
    #pragma unroll
    for (int mt = 0; mt < 4; ++mt)
      #pragma unroll
      for (int r = 0; r < 4; ++r) {
        red[wave - 1][mt * 4 + r][lane]      = accT[mt][r];
        red[wave - 1][16 + mt * 4 + r][lane] = accG[mt][r];
      }
  }
  __syncthreads();
  if (wave == 0) {
    const int base = blockIdx.y * 524288;
    #pragma unroll
    for (int mt = 0; mt < 4; ++mt) {
      #pragma unroll
      for (int r = 0; r < 4; ++r) {
        float t = accT[mt][r] + red[0][mt * 4 + r][lane]
                              + red[1][mt * 4 + r][lane]
                              + red[2][mt * 4 + r][lane];
        float g = accG[mt][r] + red[0][16 + mt * 4 + r][lane]
                              + red[1][16 + mt * 4 + r][lane]
                              + red[2][16 + mt * 4 + r][lane];
        int b = mt * 16 + quad * 4 + r;          // C/D: row = quad*4 + reg
        pT[base + b * 8192 + ff] = t;
        pG[base + b * 8192 + ff] = g;
      }
    }
  }
}

// ---------------------------------------------------------------------------
// K1c: combine the 2 K-halves, apply silu product, write mod; fused per-block
// abs-partials (256-chunk) -> part2 so k1b shrinks to one tiny block.
// ---------------------------------------------------------------------------
__global__ __launch_bounds__(256) void k1c_combine(
    const float* __restrict__ pT, const float* __restrict__ pG,
    float* __restrict__ mod, float* __restrict__ part2)
{
  const int tid = threadIdx.x;
  const int g = blockIdx.x * 256 + tid;
  float t  = pT[g] + pT[g + 524288];
  float gg = pG[g] + pG[g + 524288];
  float m = t * gg / (1.0f + __expf(-gg));
  mod[g] = m;
  float a = fabsf(m);
  #pragma unroll
  for (int o = 1; o < 64; o <<= 1) a += __shfl_xor(a, o, 64);
  __shared__ float ws[4];
  if ((tid & 63) == 0) ws[tid >> 6] = a;
  __syncthreads();
  if (tid == 0) part2[blockIdx.x] = ws[0] + ws[1] + ws[2] + ws[3];
}

// ---------------------------------------------------------------------------
// K1b: s[row] = rsqrt(mean + eps) from 8 part2 chunks. One block.
// ---------------------------------------------------------------------------
__global__ __launch_bounds__(256) void k1b_scale(const float* __restrict__ part2,
                                                 float* __restrict__ s)
{
  const int row = threadIdx.x;   // 256 rows = (b,k)
  float t = 0.0f;
  #pragma unroll
  for (int c = 0; c < 8; ++c) t += part2[row * 8 + c];
  s[row] = rsqrtf(t * (1.0f / 2048.0f) + 1e-4f);
}

// ---------------------------------------------------------------------------
// K2: partial[b*8+jc] = block sum of sqrt(re^2+im^2+eps). No atomics.
// ---------------------------------------------------------------------------
__global__ __launch_bounds__(256) void k2_mag(
    const float* __restrict__ mod, const float* __restrict__ s,
    const float* __restrict__ wstat,
    const float* __restrict__ wmod,
    const float* __restrict__ cw,
    const float* __restrict__ cb,
    float* __restrict__ partial)
{
  const int b = blockIdx.x, jc = blockIdx.y;
  const int tid = threadIdx.x;
  __shared__ __align__(16) float a_l[256 * 8];

  float weff[4]; float beff = 0.0f;
  #pragma unroll
  for (int r = 0; r < 4; ++r) {
    weff[r] = cw[r] + cw[4 + r] + cw[8 + r] + cw[12 + r];
    beff += cb[r];
  }
  const float s0 = s[b * 4 + 0], s1 = s[b * 4 + 1];
  const float* mb = mod + b * 8192;

  #pragma unroll
  for (int p = 0; p < 8; ++p) {
    int k = p >> 2, r = p & 3;
    float sc = (k ? s1 : s0) * weff[r];
    a_l[tid * 8 + p] = mb[k * 2048 + r * 512 + tid] * sc;
  }
  const int j = jc * 32 + (tid & 31);
  float bp[8];
  #pragma unroll
  for (int p = 0; p < 8; ++p) {
    int k = p >> 2, r = p & 3;
    bp[p] = mb[k * 2048 + r * 512 + 256 + j] * (k ? s1 : s0);
  }
  __syncthreads();

  const int ioff = tid >> 5;
  float acc = 0.0f;
  for (int it = 0; it < 32; ++it) {
    const int i = it * 8 + ioff;
    const float4 av0 = *reinterpret_cast<const float4*>(&a_l[i * 8]);
    const float4 av1 = *reinterpret_cast<const float4*>(&a_l[i * 8 + 4]);
    float d0 = av0.x * bp[0] + av0.y * bp[1] + av0.z * bp[2] + av0.w * bp[3];
    float d1 = av1.x * bp[4] + av1.y * bp[5] + av1.z * bp[6] + av1.w * bp[7];
    const int ij = i * 256 + j;
    float m0 = wmod[ij] * (d0 + beff);
    float m1 = wmod[65536 + ij] * (d1 + beff);
    float2 a1 = *reinterpret_cast<const float2*>(wstat + 131072 + ij * 2);
    float re = a1.x * m0 - a1.y * m1;
    float im = a1.x * m1 - a1.y * m0;
    acc += sqrtf(re * re + im * im + 1e-4f);
  }
  #pragma unroll
  for (int o = 1; o < 64; o <<= 1) acc += __shfl_xor(acc, o, 64);
  __shared__ float wsum[4];
  if ((tid & 63) == 0) wsum[tid >> 6] = acc;
  __syncthreads();
  if (tid == 0) partial[b * 8 + jc] = wsum[0] + wsum[1] + wsum[2] + wsum[3];
}

// ---------------------------------------------------------------------------
// K4: final output (fp32). grid (64 b, 8 i-chunks of 32).
// ---------------------------------------------------------------------------
__global__ __launch_bounds__(256) void k4_out(
    const float* __restrict__ mod, const float* __restrict__ s,
    const float* __restrict__ wstat,
    const float* __restrict__ wmod,
    const float* __restrict__ cw,
    const float* __restrict__ cb,
    const float* __restrict__ partial,
    float* __restrict__ out)
{
  const int b = blockIdx.x, ibase = blockIdx.y * 32;
  const int tid = threadIdx.x;
  __shared__ __align__(16) float a_l[32 * 16];

  float weff[4]; float beff = 0.0f;
  #pragma unroll
  for (int r = 0; r < 4; ++r) {
    weff[r] = cw[r] + cw[4 + r] + cw[8 + r] + cw[12 + r];
    beff += cb[r];
  }
  float sk[4];
  #pragma unroll
  for (int k = 0; k < 4; ++k) sk[k] = s[b * 4 + k];
  const float* mb = mod + b * 8192;

  float tot = 0.0f;
  #pragma unroll
  for (int t = 0; t < 8; ++t) tot += partial[b * 8 + t];
  const float inv = rsqrtf(tot * (1.0f / 65536.0f) + 1e-4f);

  #pragma unroll
  for (int p = 0; p < 2; ++p) {
    int idx = p * 256 + tid;
    int il = idx & 31, kr = idx >> 5;
    int k = kr >> 2, r = kr & 3;
    a_l[il * 16 + kr] = mb[k * 2048 + r * 512 + ibase + il] * (sk[k] * weff[r]);
  }
  const int j = (tid & 127) * 2;
  const int ioff = tid >> 7;
  float bp0[16], bp1[16];
  #pragma unroll
  for (int kr = 0; kr < 16; ++kr) {
    int k = kr >> 2, r = kr & 3;
    float2 v = *reinterpret_cast<const float2*>(mb + k * 2048 + r * 512 + 256 + j);
    bp0[kr] = v.x * sk[k]; bp1[kr] = v.y * sk[k];
  }
  __syncthreads();

  #pragma unroll 2
  for (int it = 0; it < 16; ++it) {
    const int il = it * 2 + ioff;
    const int i = ibase + il;
    const float4 a0 = *reinterpret_cast<const float4*>(&a_l[il * 16]);
    const float4 a1 = *reinterpret_cast<const float4*>(&a_l[il * 16 + 4]);
    const float4 a2 = *reinterpret_cast<const float4*>(&a_l[il * 16 + 8]);
    const float4 a3 = *reinterpret_cast<const float4*>(&a_l[il * 16 + 12]);
    const int ij = i * 256 + j;
    const float2 wm0 = *reinterpret_cast<const float2*>(wmod + ij);
    const float2 wm1 = *reinterpret_cast<const float2*>(wmod + 65536 + ij);
    const float2 wm2 = *reinterpret_cast<const float2*>(wmod + 131072 + ij);
    const float2 wm3 = *reinterpret_cast<const float2*>(wmod + 196608 + ij);
    const float4 A0v = *reinterpret_cast<const float4*>(wstat + ij * 2);
    const float4 A1v = *reinterpret_cast<const float4*>(wstat + 131072 + ij * 2);
    float outv[2];
    #pragma unroll
    for (int e = 0; e < 2; ++e) {
      const float* bp = e ? bp1 : bp0;
      float d0 = a0.x * bp[0] + a0.y * bp[1] + a0.z * bp[2] + a0.w * bp[3];
      float d1 = a1.x * bp[4] + a1.y * bp[5] + a1.z * bp[6] + a1.w * bp[7];
      float d2 = a2.x * bp[8] + a2.y * bp[9] + a2.z * bp[10] + a2.w * bp[11];
      float d3 = a3.x * bp[12] + a3.y * bp[13] + a3.z * bp[14] + a3.w * bp[15];
      float m0 = (e ? wm0.y : wm0.x) * (d0 + beff);
      float m1 = (e ? wm1.y : wm1.x) * (d1 + beff);
      float m2 = (e ? wm2.y : wm2.x) * (d2 + beff);
      float m3 = (e ? wm3.y : wm3.x) * (d3 + beff);
      float A0r = e ? A0v.z : A0v.x;
      float A0i = e ? A0v.w : A0v.y;
      float A1r = e ? A1v.z : A1v.x;
      float A1i = e ? A1v.w : A1v.y;
      float re = A1r * m0 - A1i * m1;
      float im = A1r * m1 - A1i * m0;
      float mwre = A0r + re * inv;
      float mwim = A0i + im * inv;
      float rd = rsqrtf(m2 * m2 + m3 * m3 + 1e-4f);
      outv[e] = (mwre * m2 + mwim * m3) * rd;
    }
    *reinterpret_cast<float2*>(out + b * 65536 + ij) = make_float2(outv[0], outv[1]);
  }
}

extern "C" void kernel_launch(void* const* d_in, const int* in_sizes, int n_in,
                              void* d_out, int out_size, void* d_ws, size_t ws_size,
                              hipStream_t stream) {
  const float* x     = (const float*)d_in[0];
  const float* Wt    = (const float*)d_in[1];
  const float* Wg    = (const float*)d_in[2];
  const float* wstat = (const float*)d_in[3];
  const float* wmod  = (const float*)d_in[4];
  const float* cw    = (const float*)d_in[5];
  const float* cb    = (const float*)d_in[6];

  float* pT      = (float*)d_ws;           // 2 x 524288 floats
  float* pG      = pT + 1048576;           // 2 x 524288 floats
  float* mod     = pG + 1048576;           // 524288 floats
  float* part2   = mod + 524288;           // 2048 floats
  float* sbuf    = part2 + 2048;           // 256 floats
  float* partial = sbuf + 256;             // 512 floats

  k1_gemm    <<<dim3(512, 2), 256, 0, stream>>>(x, Wt, Wg, pT, pG);
  k1c_combine<<<2048, 256, 0, stream>>>(pT, pG, mod, part2);
  k1b_scale  <<<1, 256, 0, stream>>>(part2, sbuf);
  k2_mag     <<<dim3(64, 8), 256, 0, stream>>>(mod, sbuf, wstat, wmod, cw, cb, partial);
  k4_out     <<<dim3(64, 8), 256, 0, stream>>>(mod, sbuf, wstat, wmod, cw, cb, partial,
                                               (float*)d_out);
}